// Round 12
// baseline (135.818 us; speedup 1.0000x reference)
//
#include <hip/hip_runtime.h>
#include <stdint.h>

// DiffAttention: O[n,h,d] = sum_l sigmoid(q_n.k_l) v_l / sum_l sigmoid(q_n.k_l)
// N=L=4096, H=8, M=D=64, fp32 in/out, bf16 MFMA compute.
//
// R12: BARRIER-FREE free-running waves. All barrier-preserving variants
// (R4/R6/R7/R9/R11) land at 53-61us = SUM of pipes (VALU 27 + MFMA 14 +
// LDS 13): barriers phase-lock all waves into the same pipe simultaneously.
// Fix: single-wave workgroups (64 thr), each wave owns 64 q-rows and stages
// its own private 8KB K/V 32l-tile via global_load_lds (async DMA; R8 showed
// direct global->VGPR loads expose L2 latency synchronously instead).
// Per-wave ordering via explicit s_waitcnt inline-asm (memory clobber).
// No __syncthreads anywhere -> waves de-phase -> pipes overlap (m114).
// V image is 32l-tile-major [h][t32][d][l'32] (4KB contiguous per tile),
// pi-permuted l (swap bits 2,3) so PV A-frag = sigmoid output regs packed
// (chunk c = pk[4c..4c+3], re-verified for 32l), 2-bit chunk swizzle c^(d&3).
// Standing lessons: R3 spill cliff; R5 no __threadfence split-K; R8 no
// direct-global frags; paired-rcp (R10) reverted.

typedef __bf16 bf16x8 __attribute__((ext_vector_type(8)));
typedef __bf16 bf16x2 __attribute__((ext_vector_type(2)));
typedef float  f32x2  __attribute__((ext_vector_type(2)));
typedef float  f32x16 __attribute__((ext_vector_type(16)));
typedef unsigned u32x4 __attribute__((ext_vector_type(4)));

constexpr int NH = 8, MD = 64, NL = 4096, NN = 4096;
constexpr size_t ONUM_ELEMS = (size_t)NN * NH * MD;  // per split (bf16)
constexpr size_t Z_ELEMS    = (size_t)NN * NH;       // per split (f32)
constexpr size_t KB_ELEMS   = (size_t)NH * NL * MD;  // bf16
constexpr size_t VTB_ELEMS  = (size_t)NH * NL * MD;  // bf16

__device__ __forceinline__ unsigned packbf2(float a, float b) {
  bf16x2 t = __builtin_convertvector((f32x2){a, b}, bf16x2);
  return __builtin_bit_cast(unsigned, t);
}

__device__ __forceinline__ void glds16(const void* g, void* l) {
  __builtin_amdgcn_global_load_lds(
      (const __attribute__((address_space(1))) unsigned int*)g,
      (__attribute__((address_space(3))) unsigned int*)l, 16, 0, 0);
}

// ---------------- prepass: one block per (h, 64l-block) ----------------
__global__ __launch_bounds__(256) void diffattn_prepass(
    const float* __restrict__ Kg, const float* __restrict__ Vg,
    unsigned short* __restrict__ Kb, unsigned short* __restrict__ Vtb) {
  __shared__ __attribute__((aligned(16))) unsigned short Vt_lds[64 * 64];
  const int tid = threadIdx.x;
  const int h = blockIdx.x & 7;
  const int t = blockIdx.x >> 3;

  // ---- K: [l][h][m] fp32 -> [h][l][m] bf16, 16B chunks swizzled by l&7
#pragma unroll
  for (int e = 0; e < 2; ++e) {
    const int g = tid * 2 + e;
    const int l = g >> 3, c = g & 7;
    const float* kp = Kg + (((size_t)(t * 64 + l) * NH + h) * MD) + c * 8;
    const float4 a = *(const float4*)kp;
    const float4 b = *(const float4*)(kp + 4);
    unsigned out[4] = {packbf2(a.x, a.y), packbf2(a.z, a.w),
                       packbf2(b.x, b.y), packbf2(b.z, b.w)};
    unsigned short* dst =
        Kb + ((size_t)h * NL + t * 64 + l) * MD + ((c ^ (l & 7)) * 8);
    *(uint4*)dst = *(const uint4*)out;
  }

  // ---- V: [l][h][d] fp32 -> LDS transpose (pi: swap bits 2,3 of l) ->
  //      32l-tile-major [h][t32][d][l'32] bf16, 2-bit chunk swizzle c^(d&3)
  {
    const int lr = tid & 63, dbase = (tid >> 6) * 16;
    const int pl = (lr & 0x33) | ((lr & 4) << 1) | ((lr & 8) >> 1);
    const float* vp = Vg + (((size_t)(t * 64 + lr) * NH + h) * MD) + dbase;
#pragma unroll
    for (int i = 0; i < 4; ++i) {
      const float4 v = *(const float4*)(vp + i * 4);
      const int d0 = dbase + i * 4;
      Vt_lds[(d0 + 0) * 64 + pl] = __builtin_bit_cast(unsigned short, (__bf16)v.x);
      Vt_lds[(d0 + 1) * 64 + pl] = __builtin_bit_cast(unsigned short, (__bf16)v.y);
      Vt_lds[(d0 + 2) * 64 + pl] = __builtin_bit_cast(unsigned short, (__bf16)v.z);
      Vt_lds[(d0 + 3) * 64 + pl] = __builtin_bit_cast(unsigned short, (__bf16)v.w);
    }
  }
  __syncthreads();
#pragma unroll
  for (int e = 0; e < 2; ++e) {
    const int g = tid * 2 + e;          // 0..511: (d, half, chunk)
    const int d = g >> 3, hf = (g >> 2) & 1, c = g & 3;
    const uint4 chunk = *(const uint4*)&Vt_lds[d * 64 + hf * 32 + c * 8];
    unsigned short* dst = Vtb +
        (((size_t)(h * 128 + t * 2 + hf) * 64 + d) * 32) + ((c ^ (d & 3)) * 8);
    *(uint4*)dst = chunk;
  }
}

// ---------------- partial: single-wave blocks, no barriers ----------------
__global__ __launch_bounds__(64, 3) void diffattn_partial(
    const float* __restrict__ Qg, const unsigned short* __restrict__ Kb,
    const unsigned short* __restrict__ Vtb, unsigned short* __restrict__ Onum,
    float* __restrict__ Zp, int nsplit, int lLen) {
  __shared__ __attribute__((aligned(16))) unsigned short Ksh[32 * 64];  // 4KB
  __shared__ __attribute__((aligned(16))) unsigned short Vsh[64 * 32];  // 4KB

  const int lane = threadIdx.x;
  const int col  = lane & 31;
  const int hi   = lane >> 5;

  const int h     = blockIdx.x & 7;
  const int r     = blockIdx.x >> 3;
  const int split = r % nsplit;
  const int qt    = r / nsplit;
  const int n0    = qt * 64;
  const int lBeg  = split * lLen;
  const int T     = lLen >> 5;  // 32-l tiles

  // Q fragments (B operand) for both q-halves, prescaled by -log2e.
  bf16x8 qf[2][4];
#pragma unroll
  for (int half = 0; half < 2; ++half) {
    const float* qp = Qg + ((size_t)(n0 + half * 32 + col) * NH + h) * MD;
    const float c = -1.4426950408889634f;
#pragma unroll
    for (int kc = 0; kc < 4; ++kc) {
      const float4 x = *(const float4*)(qp + kc * 16 + hi * 8);
      const float4 y = *(const float4*)(qp + kc * 16 + hi * 8 + 4);
      bf16x8 f;
      f[0] = (__bf16)(c * x.x); f[1] = (__bf16)(c * x.y);
      f[2] = (__bf16)(c * x.z); f[3] = (__bf16)(c * x.w);
      f[4] = (__bf16)(c * y.x); f[5] = (__bf16)(c * y.y);
      f[6] = (__bf16)(c * y.z); f[7] = (__bf16)(c * y.w);
      qf[half][kc] = f;
    }
  }

  f32x16 oacc[2][2];  // [q-half][ds]
#pragma unroll
  for (int a = 0; a < 2; ++a)
#pragma unroll
    for (int b = 0; b < 2; ++b)
#pragma unroll
      for (int i = 0; i < 16; ++i) oacc[a][b][i] = 0.f;
  float zacc[2] = {0.f, 0.f};
  const f32x16 zfc = {};

  const char* kg = (const char*)Kb + (size_t)h * NL * MD * 2 + (size_t)lBeg * 128;
  const char* vg = (const char*)Vtb + (size_t)h * NL * MD * 2 +
                   ((size_t)(lBeg >> 5)) * 4096;

  auto prefetch = [&](int t) {
    const char* ks = kg + (size_t)t * 4096;
    const char* vs = vg + (size_t)t * 4096;
#pragma unroll
    for (int i = 0; i < 4; ++i)
      glds16(ks + i * 1024 + lane * 16, (char*)Ksh + i * 1024);
#pragma unroll
    for (int i = 0; i < 4; ++i)
      glds16(vs + i * 1024 + lane * 16, (char*)Vsh + i * 1024);
  };

  prefetch(0);

  for (int t = 0; t < T; ++t) {
    // my own glds for tile t landed (issued last iter; latency hidden by
    // last tile's compute). Per-wave wait, no barrier.
    __asm__ volatile("s_waitcnt vmcnt(0)" ::: "memory");

    // read the whole tile into registers (buffer is single: must finish
    // reads before overwriting with prefetch(t+1))
    const int swk = col & 7;
    bf16x8 kf[4];
#pragma unroll
    for (int kc = 0; kc < 4; ++kc)
      kf[kc] = *(const bf16x8*)((const char*)Ksh + col * 128 +
                                ((((kc << 1) | hi) ^ swk) * 16));
    bf16x8 vf[2][2];
#pragma unroll
    for (int c = 0; c < 2; ++c)
#pragma unroll
      for (int ds = 0; ds < 2; ++ds) {
        const int d = ds * 32 + col;
        vf[c][ds] = *(const bf16x8*)((const char*)Vsh + d * 64 +
                                     ((((c << 1) | hi) ^ (d & 3)) * 16));
      }
    __asm__ volatile("s_waitcnt lgkmcnt(0)" ::: "memory");
    if (t + 1 < T) prefetch(t + 1);

#pragma unroll
    for (int half = 0; half < 2; ++half) {
      // QK: D1 (32l x 32q) = K(32l x 64m) x Qscaled(64m x 32q)
      f32x16 d1 = __builtin_amdgcn_mfma_f32_32x32x16_bf16(kf[0], qf[half][0],
                                                          zfc, 0, 0, 0);
#pragma unroll
      for (int kc = 1; kc < 4; ++kc)
        d1 = __builtin_amdgcn_mfma_f32_32x32x16_bf16(kf[kc], qf[half][kc],
                                                     d1, 0, 0, 0);
      // sigmoid + Z + pack (reg order == pi order)
      unsigned pk[8];
#pragma unroll
      for (int p = 0; p < 8; ++p) {
        const float eA = __builtin_amdgcn_exp2f(d1[2 * p]);
        const float eB = __builtin_amdgcn_exp2f(d1[2 * p + 1]);
        const float sa = __builtin_amdgcn_rcpf(1.0f + eA);
        const float sb = __builtin_amdgcn_rcpf(1.0f + eB);
        zacc[half] += sa + sb;
        pk[p] = packbf2(sa, sb);
      }
      // PV: O += P(32q x 32l) x V(32l x 64d); A-frag chunk c = pk[4c..4c+3]
#pragma unroll
      for (int c = 0; c < 2; ++c) {
        const bf16x8 pf = __builtin_bit_cast(bf16x8, *(const u32x4*)&pk[c * 4]);
#pragma unroll
        for (int ds = 0; ds < 2; ++ds)
          oacc[half][ds] = __builtin_amdgcn_mfma_f32_32x32x16_bf16(
              pf, vf[c][ds], oacc[half][ds], 0, 0, 0);
      }
    }
  }

  // ---- epilogue: bf16 numerator + f32 Z partials
#pragma unroll
  for (int half = 0; half < 2; ++half) {
    const float zrow = zacc[half] + __shfl_xor(zacc[half], 32, 64);
    if (hi == 0)
      Zp[(size_t)split * Z_ELEMS +
         (size_t)(n0 + half * 32 + col) * NH + h] = zrow;
  }
  unsigned short* onum = Onum + (size_t)split * ONUM_ELEMS;
#pragma unroll
  for (int half = 0; half < 2; ++half)
#pragma unroll
    for (int ds = 0; ds < 2; ++ds) {
      const int d = ds * 32 + col;
#pragma unroll
      for (int r2 = 0; r2 < 16; ++r2) {
        const int row = (r2 & 3) + 8 * (r2 >> 2) + 4 * hi;
        onum[((size_t)(n0 + half * 32 + row) * NH + h) * MD + d] =
            __builtin_bit_cast(unsigned short, (__bf16)oacc[half][ds][r2]);
      }
    }
}

// ---------------- combine: one 8-elem bf16 chunk per thread ----------------
__global__ __launch_bounds__(256) void diffattn_combine(
    const unsigned short* __restrict__ Onum, const float* __restrict__ Zp,
    float* __restrict__ Og, int nsplit) {
  const int idx = blockIdx.x * 256 + threadIdx.x;
  if (idx >= (int)(ONUM_ELEMS / 8)) return;
  const int nh = idx >> 3;
  const int c8 = (idx & 7) * 8;
  float z = 0.f;
  float acc[8] = {0.f, 0.f, 0.f, 0.f, 0.f, 0.f, 0.f, 0.f};
  for (int s = 0; s < nsplit; ++s) {
    z += Zp[(size_t)s * Z_ELEMS + nh];
    const uint4 t = *(const uint4*)(Onum + (size_t)s * ONUM_ELEMS +
                                    (size_t)nh * MD + c8);
    const unsigned u[4] = {t.x, t.y, t.z, t.w};
#pragma unroll
    for (int j = 0; j < 4; ++j) {
      acc[2 * j]     += __builtin_bit_cast(float, u[j] << 16);
      acc[2 * j + 1] += __builtin_bit_cast(float, u[j] & 0xffff0000u);
    }
  }
  const float zi = __builtin_amdgcn_rcpf(z);
  float4 r0 = make_float4(acc[0] * zi, acc[1] * zi, acc[2] * zi, acc[3] * zi);
  float4 r1 = make_float4(acc[4] * zi, acc[5] * zi, acc[6] * zi, acc[7] * zi);
  float* out = Og + (size_t)nh * MD + c8;
  *(float4*)out = r0;
  *(float4*)(out + 4) = r1;
}

extern "C" void kernel_launch(void* const* d_in, const int* in_sizes, int n_in,
                              void* d_out, int out_size, void* d_ws, size_t ws_size,
                              hipStream_t stream) {
  const float* Q = (const float*)d_in[0];
  const float* K = (const float*)d_in[1];
  const float* V = (const float*)d_in[2];
  float* O = (float*)d_out;

  const size_t conv_bytes = (KB_ELEMS + VTB_ELEMS) * sizeof(unsigned short);
  int nsplit = 8;
  while (nsplit > 1 &&
         (size_t)nsplit * (ONUM_ELEMS * 2 + Z_ELEMS * 4) + conv_bytes > ws_size)
    nsplit >>= 1;

  unsigned short* Onum = (unsigned short*)d_ws;
  float* Zp = (float*)(Onum + (size_t)nsplit * ONUM_ELEMS);
  unsigned short* Kbb = (unsigned short*)(Zp + (size_t)nsplit * Z_ELEMS);
  unsigned short* Vtb = Kbb + KB_ELEMS;

  const int lLen = NL / nsplit;
  diffattn_prepass<<<dim3(8 * (NL / 64)), dim3(256), 0, stream>>>(K, V, Kbb, Vtb);
  // one wave per block: 8 heads x 64 q-tiles(64 rows) x nsplit
  diffattn_partial<<<dim3(8 * (NN / 64) * nsplit), dim3(64), 0, stream>>>(
      Q, Kbb, Vtb, Onum, Zp, nsplit, lLen);
  diffattn_combine<<<dim3((ONUM_ELEMS / 8 + 255) / 256), dim3(256), 0, stream>>>(
      Onum, Zp, O, nsplit);
}